// Round 5
// baseline (987.829 us; speedup 1.0000x reference)
//
#include <hip/hip_runtime.h>
#include <cstdint>

#define BATCH 8
#define NPTS  4096
#define MPTS  1024
#define DIM   64

typedef float v2f __attribute__((ext_vector_type(2)));
typedef unsigned long long u64;
typedef unsigned int u32;

// Pack (f32 distance bits, aux) into a double whose VALUE ordering equals the
// u64 bit-pattern ordering: hi word = f32 bits of a non-negative float
// (<= FLT_MAX bits -> f64 exponent <= 2039, sign 0 -> positive finite double).
// v_max_f64 / v_min_f64 then give exact u64 max/min in ONE instruction.
// __hiloint2double lowers to plain register-pair formation (no shift/or fat).
__device__ __forceinline__ double mk_key(float m, u32 aux) {
  return __hiloint2double((int)__float_as_uint(m), (int)aux);
}
__device__ __forceinline__ u32 key_lo(double d) {
  return (u32)__double2loint(d);
}

// One DPP step of a 64-lane f64-key max reduction. bound_ctrl=true -> invalid
// source lanes read 0.0, the identity for max of positive keys.
#define WAVE_MAX_F64_STEP(x, ctrl)                                                   \
  {                                                                                  \
    const int lo_ = __builtin_amdgcn_update_dpp(0, __double2loint(x), (ctrl), 0xf, 0xf, true); \
    const int hi_ = __builtin_amdgcn_update_dpp(0, __double2hiint(x), (ctrl), 0xf, 0xf, true); \
    const double y_ = __hiloint2double(hi_, lo_);                                    \
    (x) = fmax((x), y_);                                                             \
  }

// -------------------- Kernel 1: farthest point sampling --------------------
// TWO independent clouds per block (4 blocks total): the two FPS chains are
// independent, so cloud B's distance-compute issue fills cloud A's LDS/global
// latency stalls and vice versa; one barrier serves both. Winner coords are
// fetched from global pos (L2-hot ~220cy, fully overlapped between chains)
// instead of an LDS mirror. 256 threads, 16 pts/thread/cloud as 8 float2
// groups (v_pk_* fp32 = identical IEEE rounding to scalar, contract off).
// Argmax key: (dist_bits<<32)|~idx -> max = largest dist, tie -> smallest idx
// (matches np.argmax). 64-bit maxes via single v_max_f64 (see mk_key).
__global__ __launch_bounds__(256, 1) void fps_kernel(const float* __restrict__ pos,
                                                     int* __restrict__ gidx) {
#pragma clang fp contract(off)
  const int b0 = blockIdx.x * 2, b1 = b0 + 1;
  const int t = threadIdx.x;
  const float* pA = pos + (size_t)b0 * NPTS * 3;
  const float* pB = pos + (size_t)b1 * NPTS * 3;

  __shared__ double redA[2][4], redB[2][4];

  v2f ax[8], ay[8], az[8], am[8];
  v2f bx[8], by[8], bz[8], bm[8];
  u32 aux[16];  // ~local_idx constants, shared between both clouds
#pragma unroll
  for (int k = 0; k < 16; ++k) {
    const int i = t + k * 256;
    aux[k] = ~(u32)i;
    ax[k >> 1][k & 1] = pA[3 * i + 0];
    ay[k >> 1][k & 1] = pA[3 * i + 1];
    az[k >> 1][k & 1] = pA[3 * i + 2];
    bx[k >> 1][k & 1] = pB[3 * i + 0];
    by[k >> 1][k & 1] = pB[3 * i + 1];
    bz[k >> 1][k & 1] = pB[3 * i + 2];
    am[k >> 1][k & 1] = 3.402823466e+38f;  // finfo(float32).max
    bm[k >> 1][k & 1] = 3.402823466e+38f;
  }

  if (t == 0) {  // deterministic start at local idx 0
    gidx[b0 * MPTS] = b0 * NPTS;
    gidx[b1 * MPTS] = b1 * NPTS;
  }
  float lxA = pA[0], lyA = pA[1], lzA = pA[2];
  float lxB = pB[0], lyB = pB[1], lzB = pB[2];

  for (int it = 1; it < MPTS; ++it) {
    const int buf = it & 1;
    // ---- cloud A: dist+min update, local key tree, DPP wave reduce ----
    double bestA;
    {
      const v2f vx = {lxA, lxA}, vy = {lyA, lyA}, vz = {lzA, lzA};
      double pg[8];
#pragma unroll
      for (int g = 0; g < 8; ++g) {
        // strict fp32, no contraction: ((dx*dx + dy*dy) + dz*dz)
        const v2f dx = ax[g] - vx;
        const v2f dy = ay[g] - vy;
        const v2f dz = az[g] - vz;
        const v2f d = (dx * dx + dy * dy) + dz * dz;
        const v2f m = __builtin_elementwise_min(am[g], d);
        am[g] = m;
        pg[g] = fmax(mk_key(m[0], aux[2 * g]), mk_key(m[1], aux[2 * g + 1]));
      }
      bestA = fmax(fmax(fmax(pg[0], pg[1]), fmax(pg[2], pg[3])),
                   fmax(fmax(pg[4], pg[5]), fmax(pg[6], pg[7])));
      WAVE_MAX_F64_STEP(bestA, 0x111);  // row_shr:1
      WAVE_MAX_F64_STEP(bestA, 0x112);  // row_shr:2
      WAVE_MAX_F64_STEP(bestA, 0x114);  // row_shr:4
      WAVE_MAX_F64_STEP(bestA, 0x118);  // row_shr:8
      WAVE_MAX_F64_STEP(bestA, 0x142);  // row_bcast:15
      WAVE_MAX_F64_STEP(bestA, 0x143);  // row_bcast:31
    }
    // ---- cloud B: independent chain, interleaves with A's stalls ----
    double bestB;
    {
      const v2f vx = {lxB, lxB}, vy = {lyB, lyB}, vz = {lzB, lzB};
      double pg[8];
#pragma unroll
      for (int g = 0; g < 8; ++g) {
        const v2f dx = bx[g] - vx;
        const v2f dy = by[g] - vy;
        const v2f dz = bz[g] - vz;
        const v2f d = (dx * dx + dy * dy) + dz * dz;
        const v2f m = __builtin_elementwise_min(bm[g], d);
        bm[g] = m;
        pg[g] = fmax(mk_key(m[0], aux[2 * g]), mk_key(m[1], aux[2 * g + 1]));
      }
      bestB = fmax(fmax(fmax(pg[0], pg[1]), fmax(pg[2], pg[3])),
                   fmax(fmax(pg[4], pg[5]), fmax(pg[6], pg[7])));
      WAVE_MAX_F64_STEP(bestB, 0x111);
      WAVE_MAX_F64_STEP(bestB, 0x112);
      WAVE_MAX_F64_STEP(bestB, 0x114);
      WAVE_MAX_F64_STEP(bestB, 0x118);
      WAVE_MAX_F64_STEP(bestB, 0x142);
      WAVE_MAX_F64_STEP(bestB, 0x143);
    }

    if ((t & 63) == 63) {
      redA[buf][t >> 6] = bestA;
      redB[buf][t >> 6] = bestB;
    }
    __syncthreads();

    // combines + winner-coord fetches for A and B are independent -> overlap
    const double cA = fmax(fmax(redA[buf][0], redA[buf][1]),
                           fmax(redA[buf][2], redA[buf][3]));
    const double cB = fmax(fmax(redB[buf][0], redB[buf][1]),
                           fmax(redB[buf][2], redB[buf][3]));
    const u32 wA = ~key_lo(cA);
    const u32 wB = ~key_lo(cB);
    const float3 qa = *(const float3*)(pA + 3 * (size_t)wA);  // L2-hot broadcast
    const float3 qb = *(const float3*)(pB + 3 * (size_t)wB);
    lxA = qa.x; lyA = qa.y; lzA = qa.z;
    lxB = qb.x; lyB = qb.y; lzB = qb.z;
    if (t == 0) {
      gidx[b0 * MPTS + it] = b0 * NPTS + (int)wA;
      gidx[b1 * MPTS + it] = b1 * NPTS + (int)wB;
    }
  }
}

// -------------- Kernel 2: k=1 NN + output assembly (fused) -----------------
// B*32 blocks x 256 threads. Phase 1: 128 hr points/block, 2 threads per
// point splitting the M=1024 lr points in half; packed fp32; argmin key
// (dist_bits<<32)|j -> min = smallest dist, tie -> smallest j (np.argmin);
// winner global index kept in LDS. Phase 2: wave-per-row assembly of the
// block's 128 rows (coalesced 256B chunks), plus zeros + batch outputs.
__global__ __launch_bounds__(256) void nn_assemble_kernel(
    const float* __restrict__ x, const float* __restrict__ pos,
    const int* __restrict__ gidx, float* __restrict__ out) {
#pragma clang fp contract(off)
  const int b = blockIdx.x >> 5;
  const int chunk = blockIdx.x & 31;
  const int t = threadIdx.x;

  __shared__ float lrx[MPTS], lry[MPTS], lrz[MPTS];
  __shared__ int snng[128];
  for (int j = t; j < MPTS; j += 256) {
    const int g = gidx[b * MPTS + j];
    lrx[j] = pos[3 * g + 0];
    lry[j] = pos[3 * g + 1];
    lrz[j] = pos[3 * g + 2];
  }
  __syncthreads();

  {
    const int pt = chunk * 128 + (t >> 1);
    const int half = t & 1;
    const int i = b * NPTS + pt;  // global hr point index
    const float px = pos[3 * i + 0];
    const float py = pos[3 * i + 1];
    const float pz = pos[3 * i + 2];
    const v2f vx = {px, px}, vy = {py, py}, vz = {pz, pz};

    double best = __hiloint2double(0x7FEFFFFF, 0xFFFFFFFF);  // +DBL_MAX > all keys
    const int j0 = half * 512;
#pragma unroll 4
    for (int s = 0; s < 256; ++s) {
      const int j = j0 + 2 * s;
      const v2f qx = *(const v2f*)&lrx[j];
      const v2f qy = *(const v2f*)&lry[j];
      const v2f qz = *(const v2f*)&lrz[j];
      const v2f dx = vx - qx;
      const v2f dy = vy - qy;
      const v2f dz = vz - qz;
      const v2f d = (dx * dx + dy * dy) + dz * dz;
      best = fmin(best, fmin(mk_key(d[0], (u32)j), mk_key(d[1], (u32)(j + 1))));
    }
    // pair combine across the two halves (lanes differ only in bit 0)
    const int blo = __shfl_xor(__double2loint(best), 1, 64);
    const int bhi = __shfl_xor(__double2hiint(best), 1, 64);
    best = fmin(best, __hiloint2double(bhi, blo));
    if (half == 0) snng[t >> 1] = gidx[b * MPTS + (int)key_lo(best)];
  }
  __syncthreads();

  // Phase 2: rows. Row = [x(64) | pos(3) | x[g](64) | pos[g](3)].
  const int wave = t >> 6, lane = t & 63;
  float* o2 = out + (size_t)BATCH * NPTS * 134;  // zeros output [B*N,3]
  float* o3 = o2 + (size_t)BATCH * NPTS * 3;     // batch output [B*N]
#pragma unroll
  for (int r = wave; r < 128; r += 4) {
    const int i = b * NPTS + chunk * 128 + r;
    const int g = snng[r];
    float* o = out + (size_t)i * 134;
    o[lane] = x[(size_t)i * DIM + lane];
    o[67 + lane] = x[(size_t)g * DIM + lane];
    if (lane < 3) {
      o[64 + lane] = pos[3 * i + lane];
      o[131 + lane] = pos[3 * g + lane];
      o2[3 * i + lane] = 0.0f;
    }
    if (lane == 0) o3[i] = (float)b;
  }
}

// ---------------------------------------------------------------------------
extern "C" void kernel_launch(void* const* d_in, const int* in_sizes, int n_in,
                              void* d_out, int out_size, void* d_ws, size_t ws_size,
                              hipStream_t stream) {
  const float* x = (const float*)d_in[0];
  const float* pos = (const float*)d_in[1];

  int* gidx = (int*)d_ws;  // [B*M] global indices of sampled points
  float* out = (float*)d_out;

  fps_kernel<<<BATCH / 2, 256, 0, stream>>>(pos, gidx);
  nn_assemble_kernel<<<BATCH * 32, 256, 0, stream>>>(x, pos, gidx, out);
}

// Round 7
// 637.164 us; speedup vs baseline: 1.5504x; 1.5504x over previous
//
#include <hip/hip_runtime.h>
#include <cstdint>

#define BATCH 8
#define NPTS  4096
#define MPTS  1024
#define DIM   64

typedef float v2f __attribute__((ext_vector_type(2)));
typedef unsigned long long u64;
typedef unsigned int u32;

// Pack (f32 distance bits, aux) into a double whose VALUE ordering equals the
// u64 bit-pattern ordering: hi word = f32 bits of a non-negative float
// (<= FLT_MAX bits -> f64 exponent <= 2039, sign 0 -> positive finite double).
// v_max_f64 / v_min_f64 then give exact u64 max/min in ONE instruction.
// __hiloint2double lowers to plain register-pair formation (no shift/or fat).
__device__ __forceinline__ double mk_key(float m, u32 aux) {
  return __hiloint2double((int)__float_as_uint(m), (int)aux);
}
__device__ __forceinline__ u32 key_lo(double d) {
  return (u32)__double2loint(d);
}

// One DPP step of a 64-lane f64-key max reduction. bound_ctrl=true -> invalid
// source lanes read 0.0, the identity for max of positive keys.
#define WAVE_MAX_F64_STEP(x, ctrl)                                                   \
  {                                                                                  \
    const int lo_ = __builtin_amdgcn_update_dpp(0, __double2loint(x), (ctrl), 0xf, 0xf, true); \
    const int hi_ = __builtin_amdgcn_update_dpp(0, __double2hiint(x), (ctrl), 0xf, 0xf, true); \
    const double y_ = __hiloint2double(hi_, lo_);                                    \
    (x) = fmax((x), y_);                                                             \
  }

// -------------------- Kernel 1: farthest point sampling --------------------
// One cloud per block (8 blocks), 512 threads = 8 waves (2/SIMD) so dependent
// VALU chains of one wave are hidden by the other wave's issue (round-5
// post-mortem: per-cloud compute ~930cy of the 1157cy iter is latency, tail
// only ~220cy). 8 pts/thread as 4 float2 groups (v_pk_* fp32 = identical IEEE
// rounding to scalar, contract off). Argmax key: (dist_bits<<32)|~idx -> max
// = largest dist, tie -> smallest idx (np.argmax). 64-bit maxes via single
// v_max_f64 (see mk_key). 6-step DPP wave reduce, lane 63 writes wave slot,
// 1 barrier (double-buffered slots), 8-slot combine, winner coords via three
// broadcast ds_read_b32 from the sx/sy/sz LDS mirror (48KB — the r1-proven
// 512-thread LDS shape; r6's 64KB float4 mirror at 512 threads core-dumped).
__global__ __launch_bounds__(512) void fps_kernel(const float* __restrict__ pos,
                                                  int* __restrict__ gidx) {
#pragma clang fp contract(off)
  const int b = blockIdx.x;
  const int t = threadIdx.x;
  const float* p = pos + (size_t)b * NPTS * 3;

  __shared__ float sx[NPTS], sy[NPTS], sz[NPTS];
  __shared__ double red[2][8];

  v2f px[4], py[4], pz[4], mind[4];
  u32 aux[8];  // ~local_idx constants
#pragma unroll
  for (int k = 0; k < 8; ++k) {
    const int i = t + k * 512;
    aux[k] = ~(u32)i;
    const float a = p[3 * i + 0];
    const float c = p[3 * i + 1];
    const float d = p[3 * i + 2];
    sx[i] = a; sy[i] = c; sz[i] = d;
    px[k >> 1][k & 1] = a;
    py[k >> 1][k & 1] = c;
    pz[k >> 1][k & 1] = d;
    mind[k >> 1][k & 1] = 3.402823466e+38f;  // finfo(float32).max
  }
  __syncthreads();

  if (t == 0) gidx[b * MPTS] = b * NPTS;  // deterministic start at local idx 0
  float lx = sx[0], ly = sy[0], lz = sz[0];

  for (int it = 1; it < MPTS; ++it) {
    const v2f vlx = {lx, lx}, vly = {ly, ly}, vlz = {lz, lz};
    double pg[4];
#pragma unroll
    for (int g = 0; g < 4; ++g) {
      // strict fp32, no contraction: ((dx*dx + dy*dy) + dz*dz), per element
      const v2f dx = px[g] - vlx;
      const v2f dy = py[g] - vly;
      const v2f dz = pz[g] - vlz;
      const v2f d = (dx * dx + dy * dy) + dz * dz;
      const v2f m = __builtin_elementwise_min(mind[g], d);
      mind[g] = m;
      pg[g] = fmax(mk_key(m[0], aux[2 * g]), mk_key(m[1], aux[2 * g + 1]));
    }
    // thread-local tree (single v_max_f64 each)
    double best = fmax(fmax(pg[0], pg[1]), fmax(pg[2], pg[3]));

    // 64-lane wave max via DPP: rows (16) then cross-row bcasts; lane 63 final.
    WAVE_MAX_F64_STEP(best, 0x111);  // row_shr:1
    WAVE_MAX_F64_STEP(best, 0x112);  // row_shr:2
    WAVE_MAX_F64_STEP(best, 0x114);  // row_shr:4
    WAVE_MAX_F64_STEP(best, 0x118);  // row_shr:8
    WAVE_MAX_F64_STEP(best, 0x142);  // row_bcast:15
    WAVE_MAX_F64_STEP(best, 0x143);  // row_bcast:31

    const int buf = it & 1;  // double-buffered slots: 1 barrier/iter
    if ((t & 63) == 63) red[buf][t >> 6] = best;
    __syncthreads();

    // 8-slot combine: 7 fmax
    const double c0 = fmax(fmax(red[buf][0], red[buf][1]),
                           fmax(red[buf][2], red[buf][3]));
    const double c1 = fmax(fmax(red[buf][4], red[buf][5]),
                           fmax(red[buf][6], red[buf][7]));
    const double c = fmax(c0, c1);
    const u32 widx = ~key_lo(c);  // low word = ~idx

    lx = sx[widx];  // broadcast reads (same address all lanes), independent
    ly = sy[widx];
    lz = sz[widx];
    if (t == 0) gidx[b * MPTS + it] = b * NPTS + (int)widx;
  }
}

// -------------- Kernel 2: k=1 NN + output assembly (fused) -----------------
// B*32 blocks x 256 threads. Phase 1: 128 hr points/block, 2 threads per
// point splitting the M=1024 lr points in half; packed fp32; argmin key
// (dist_bits<<32)|j -> min = smallest dist, tie -> smallest j (np.argmin);
// winner global index kept in LDS. Phase 2: wave-per-row assembly of the
// block's 128 rows (coalesced 256B chunks), plus zeros + batch outputs.
__global__ __launch_bounds__(256) void nn_assemble_kernel(
    const float* __restrict__ x, const float* __restrict__ pos,
    const int* __restrict__ gidx, float* __restrict__ out) {
#pragma clang fp contract(off)
  const int b = blockIdx.x >> 5;
  const int chunk = blockIdx.x & 31;
  const int t = threadIdx.x;

  __shared__ float lrx[MPTS], lry[MPTS], lrz[MPTS];
  __shared__ int snng[128];
  for (int j = t; j < MPTS; j += 256) {
    const int g = gidx[b * MPTS + j];
    lrx[j] = pos[3 * g + 0];
    lry[j] = pos[3 * g + 1];
    lrz[j] = pos[3 * g + 2];
  }
  __syncthreads();

  {
    const int pt = chunk * 128 + (t >> 1);
    const int half = t & 1;
    const int i = b * NPTS + pt;  // global hr point index
    const float px = pos[3 * i + 0];
    const float py = pos[3 * i + 1];
    const float pz = pos[3 * i + 2];
    const v2f vx = {px, px}, vy = {py, py}, vz = {pz, pz};

    double best = __hiloint2double(0x7FEFFFFF, 0xFFFFFFFF);  // +DBL_MAX > all keys
    const int j0 = half * 512;
#pragma unroll 4
    for (int s = 0; s < 256; ++s) {
      const int j = j0 + 2 * s;
      const v2f qx = *(const v2f*)&lrx[j];
      const v2f qy = *(const v2f*)&lry[j];
      const v2f qz = *(const v2f*)&lrz[j];
      const v2f dx = vx - qx;
      const v2f dy = vy - qy;
      const v2f dz = vz - qz;
      const v2f d = (dx * dx + dy * dy) + dz * dz;
      best = fmin(best, fmin(mk_key(d[0], (u32)j), mk_key(d[1], (u32)(j + 1))));
    }
    // pair combine across the two halves (lanes differ only in bit 0)
    const int blo = __shfl_xor(__double2loint(best), 1, 64);
    const int bhi = __shfl_xor(__double2hiint(best), 1, 64);
    best = fmin(best, __hiloint2double(bhi, blo));
    if (half == 0) snng[t >> 1] = gidx[b * MPTS + (int)key_lo(best)];
  }
  __syncthreads();

  // Phase 2: rows. Row = [x(64) | pos(3) | x[g](64) | pos[g](3)].
  const int wave = t >> 6, lane = t & 63;
  float* o2 = out + (size_t)BATCH * NPTS * 134;  // zeros output [B*N,3]
  float* o3 = o2 + (size_t)BATCH * NPTS * 3;     // batch output [B*N]
#pragma unroll
  for (int r = wave; r < 128; r += 4) {
    const int i = b * NPTS + chunk * 128 + r;
    const int g = snng[r];
    float* o = out + (size_t)i * 134;
    o[lane] = x[(size_t)i * DIM + lane];
    o[67 + lane] = x[(size_t)g * DIM + lane];
    if (lane < 3) {
      o[64 + lane] = pos[3 * i + lane];
      o[131 + lane] = pos[3 * g + lane];
      o2[3 * i + lane] = 0.0f;
    }
    if (lane == 0) o3[i] = (float)b;
  }
}

// ---------------------------------------------------------------------------
extern "C" void kernel_launch(void* const* d_in, const int* in_sizes, int n_in,
                              void* d_out, int out_size, void* d_ws, size_t ws_size,
                              hipStream_t stream) {
  const float* x = (const float*)d_in[0];
  const float* pos = (const float*)d_in[1];

  int* gidx = (int*)d_ws;  // [B*M] global indices of sampled points
  float* out = (float*)d_out;

  fps_kernel<<<BATCH, 512, 0, stream>>>(pos, gidx);
  nn_assemble_kernel<<<BATCH * 32, 256, 0, stream>>>(x, pos, gidx, out);
}